// Round 1
// baseline (216.978 us; speedup 1.0000x reference)
//
#include <hip/hip_runtime.h>

// Postprocess: spherical->xyz + kinematic-tree prefix sum.
// obs:  (4096, 16, 96) fp32   pred: (4096, 64, 66) fp32   out: (4096, 64, 96) fp32
// One thread per (b, t). Memory-bound: ~171 MB total traffic, floor ~27 us.

constexpr int NB = 4096;
constexpr int NT = 64;
constexpr int BT = NB * NT;          // 262144 threads
constexpr int BLOCK = 256;

__global__ __launch_bounds__(BLOCK) void postproc_kernel(
    const float* __restrict__ obs,
    const float* __restrict__ pred,
    float* __restrict__ out)
{
    const int tid = blockIdx.x * BLOCK + threadIdx.x;   // (b*64 + t)
    const int b = tid >> 6;

    // ---- load 66 pred floats (r,theta,phi x22), 8B-aligned float2s ----
    float pr[66];
    {
        const float2* p2 = reinterpret_cast<const float2*>(pred + (long)tid * 66);
        #pragma unroll
        for (int i = 0; i < 33; ++i) {
            const float2 v = p2[i];
            pr[2*i]   = v.x;
            pr[2*i+1] = v.y;
        }
    }

    float x[32][3];

    // ---- root joints from last observed frame (frame 15) ----
    {
        const float* ob = obs + (long)b * (16 * 96) + 15 * 96;
        constexpr int ic[4] = {0, 1, 6, 11};
        #pragma unroll
        for (int i = 0; i < 4; ++i) {
            #pragma unroll
            for (int c = 0; c < 3; ++c) x[ic[i]][c] = ob[ic[i]*3 + c];
        }
    }

    // ---- fused spherical->xyz + tree accumulation (topological order) ----
    // CONNECT edges; child list == E, so xyz[k] belongs to chi[k].
    constexpr int par[22] = {11,12,13,14,13,25,26,27,29,13,17,18,19,21, 1, 2, 3, 4, 6, 7, 8, 9};
    constexpr int chi[22] = {12,13,14,15,25,26,27,29,30,17,18,19,21,22, 2, 3, 4, 5, 7, 8, 9,10};
    #pragma unroll
    for (int k = 0; k < 22; ++k) {
        const float r  = pr[3*k + 0];
        const float th = pr[3*k + 1];
        const float ph = pr[3*k + 2];
        const float sp = __sinf(ph);
        const float cp = __cosf(ph);
        const float st = __sinf(th);
        const float ct = __cosf(th);
        const int c = chi[k], pa = par[k];
        const float rsp = r * sp;
        x[c][0] = fmaf(rsp, ct, x[pa][0]);   // r*sin(phi)*cos(theta)
        x[c][1] = fmaf(r,   cp, x[pa][1]);   // r*cos(phi)
        x[c][2] = fmaf(rsp, st, x[pa][2]);   // r*sin(phi)*sin(theta)
    }

    // ---- IDX_IGNORE <- IDX_EQUAL ----
    {
        constexpr int ig[6] = {16, 20, 23, 24, 28, 31};
        constexpr int eq[6] = {13, 19, 22, 13, 27, 30};
        #pragma unroll
        for (int i = 0; i < 6; ++i) {
            #pragma unroll
            for (int c = 0; c < 3; ++c) x[ig[i]][c] = x[eq[i]][c];
        }
    }

    // ---- store 96 floats as 24 float4 (tid*384 B is 16B-aligned) ----
    float* o = out + (long)tid * 96;
    #define XF(j) x[(j)/3][(j)%3]
    #pragma unroll
    for (int i = 0; i < 24; ++i) {
        const float4 v = make_float4(XF(4*i+0), XF(4*i+1), XF(4*i+2), XF(4*i+3));
        *reinterpret_cast<float4*>(o + 4*i) = v;
    }
    #undef XF
}

extern "C" void kernel_launch(void* const* d_in, const int* in_sizes, int n_in,
                              void* d_out, int out_size, void* d_ws, size_t ws_size,
                              hipStream_t stream) {
    const float* obs  = (const float*)d_in[0];   // observed_pose (4096,16,96)
    const float* pred = (const float*)d_in[1];   // pred_pose     (4096,64,66)
    float* out = (float*)d_out;                  // (4096,64,96) fp32
    postproc_kernel<<<BT / BLOCK, BLOCK, 0, stream>>>(obs, pred, out);
}